// Round 1
// baseline (298.750 us; speedup 1.0000x reference)
//
#include <hip/hip_runtime.h>
#include <hip/hip_bf16.h>
#include <stdint.h>

// Problem: out[b,c] = sum_{k<256} batchs[b,k] * label2embed[c,k]
// A = batchs [16384, 256] fp32 row-major, Bm = label2embed [4096, 256] fp32 row-major
// out [16384, 4096] fp32. GEMM-BT, K=256.
#define MDIM 16384
#define NDIM 4096
#define KDIM 256

#define BM 128
#define BN 128
#define BK 32

typedef __attribute__((ext_vector_type(8))) short bf16x8;
typedef __attribute__((ext_vector_type(4))) float f32x4;

__device__ __forceinline__ unsigned short f2bf_rne(float f) {
    union { float f; uint32_t u; } v; v.f = f;
    uint32_t u = v.u;
    u += 0x7fffu + ((u >> 16) & 1u);   // round-to-nearest-even (finite inputs)
    return (unsigned short)(u >> 16);
}

// Pass 1: fp32 -> bf16 for both inputs, into workspace. 8 elems/thread, 16B stores.
__global__ __launch_bounds__(256) void cvt_kernel(const float* __restrict__ a,
                                                  const float* __restrict__ b,
                                                  unsigned short* __restrict__ wa,
                                                  unsigned short* __restrict__ wb) {
    const int64_t nA = (int64_t)MDIM * KDIM;            // 4,194,304
    int64_t i = ((int64_t)blockIdx.x * 256 + threadIdx.x) * 8;
    const float* src; unsigned short* dst; int64_t off;
    if (i < nA) { src = a; dst = wa; off = i; }
    else        { src = b; dst = wb; off = i - nA; }
    float4 f0 = *(const float4*)(src + off);
    float4 f1 = *(const float4*)(src + off + 4);
    union { unsigned short h[8]; int4 v; } o;
    o.h[0] = f2bf_rne(f0.x); o.h[1] = f2bf_rne(f0.y);
    o.h[2] = f2bf_rne(f0.z); o.h[3] = f2bf_rne(f0.w);
    o.h[4] = f2bf_rne(f1.x); o.h[5] = f2bf_rne(f1.y);
    o.h[6] = f2bf_rne(f1.z); o.h[7] = f2bf_rne(f1.w);
    *(int4*)(dst + off) = o.v;
}

// Pass 2: m97-style bf16 MFMA GEMM-BT. 128x128 tile / block, 256 thr = 4 waves,
// each wave owns a 64x64 quadrant = 4x4 MFMA tiles of 16x16. BK=32, 8 K-steps.
// Staging via global_load_lds width=16 (wave-uniform base + lane*16 layout).
__global__ __launch_bounds__(256) void gemm_bt(const unsigned short* __restrict__ A,
                                               const unsigned short* __restrict__ Bm,
                                               float* __restrict__ out) {
    __shared__ __align__(16) unsigned short sA[BM * BK];  // 8 KiB
    __shared__ __align__(16) unsigned short sB[BN * BK];  // 8 KiB

    const int tid  = threadIdx.x;
    const int lane = tid & 63;
    const int wave = tid >> 6;
    const int wm   = wave >> 1;       // 0..1 (row quadrant)
    const int wn   = wave & 1;        // 0..1 (col quadrant)
    const int bm   = blockIdx.x >> 5;         // 128 row-tiles
    const int bn   = blockIdx.x & 31;         // 32 col-tiles

    const unsigned short* Ab = A  + (size_t)bm * BM * KDIM;
    const unsigned short* Bb = Bm + (size_t)bn * BN * KDIM;

    f32x4 acc[4][4] = {};

    const int quad = lane >> 4;       // 0..3
    const int r16  = lane & 15;       // 0..15

    for (int k0 = 0; k0 < KDIM; k0 += BK) {
        __syncthreads();  // previous iter's ds_reads done before LDS overwrite
        // Stage A and B tiles: 128 rows x 32 bf16 cols = 8192 B each.
        // chunk ch in [0,512): row = ch>>2, col = (ch&3)*8; LDS byte off = ch*16
        // -> per-wave base + lane*16 (matches global_load_lds HW placement).
#pragma unroll
        for (int c = 0; c < 2; ++c) {
            int ch  = tid + c * 256;
            int row = ch >> 2;
            int col = (ch & 3) << 3;
            __builtin_amdgcn_global_load_lds(
                (const __attribute__((address_space(1))) void*)(Ab + (size_t)row * KDIM + k0 + col),
                (__attribute__((address_space(3))) void*)(sA + ch * 8), 16, 0, 0);
            __builtin_amdgcn_global_load_lds(
                (const __attribute__((address_space(1))) void*)(Bb + (size_t)row * KDIM + k0 + col),
                (__attribute__((address_space(3))) void*)(sB + ch * 8), 16, 0, 0);
        }
        __syncthreads();  // drains vmcnt(0): staged data visible to all waves

        // Fragments: A[m = lane&15][k = quad*8 + j]  (ds_read_b128 each)
        bf16x8 af[4], bf[4];
#pragma unroll
        for (int i = 0; i < 4; ++i)
            af[i] = *(const bf16x8*)(sA + ((wm * 64 + i * 16 + r16) * BK + quad * 8));
#pragma unroll
        for (int j = 0; j < 4; ++j)
            bf[j] = *(const bf16x8*)(sB + ((wn * 64 + j * 16 + r16) * BK + quad * 8));

#pragma unroll
        for (int i = 0; i < 4; ++i)
#pragma unroll
            for (int j = 0; j < 4; ++j)
                acc[i][j] = __builtin_amdgcn_mfma_f32_16x16x32_bf16(af[i], bf[j], acc[i][j], 0, 0, 0);
    }

    // Epilogue: C/D layout col = lane&15, row = quad*4 + reg  [m89/m91]
#pragma unroll
    for (int i = 0; i < 4; ++i) {
        int rowb = bm * BM + wm * 64 + i * 16 + quad * 4;
#pragma unroll
        for (int j = 0; j < 4; ++j) {
            int colb = bn * BN + wn * 64 + j * 16 + r16;
            float* p = out + (size_t)rowb * NDIM + colb;
#pragma unroll
            for (int rr = 0; rr < 4; ++rr)
                p[(size_t)rr * NDIM] = acc[i][j][rr];
        }
    }
}

// Fallback (only if ws too small): fp32 dot, one thread per output.
__global__ __launch_bounds__(256) void naive_f32(const float* __restrict__ a,
                                                 const float* __restrict__ b,
                                                 float* __restrict__ out) {
    int64_t idx = (int64_t)blockIdx.x * 256 + threadIdx.x;
    int c = (int)(idx & (NDIM - 1));
    int r = (int)(idx >> 12);
    const float4* ap = (const float4*)(a + (size_t)r * KDIM);
    const float4* bp = (const float4*)(b + (size_t)c * KDIM);
    float s = 0.f;
#pragma unroll 8
    for (int k = 0; k < KDIM / 4; ++k) {
        float4 x = ap[k], y = bp[k];
        s += x.x * y.x + x.y * y.y + x.z * y.z + x.w * y.w;
    }
    out[idx] = s;
}

extern "C" void kernel_launch(void* const* d_in, const int* in_sizes, int n_in,
                              void* d_out, int out_size, void* d_ws, size_t ws_size,
                              hipStream_t stream) {
    const float* a = (const float*)d_in[0];   // batchs  [16384, 2, 128]
    const float* b = (const float*)d_in[1];   // label2embed [4096, 2, 128]
    float* out = (float*)d_out;               // [16384, 4096]

    const size_t need = ((size_t)MDIM + NDIM) * KDIM * sizeof(unsigned short); // 10.5 MB
    if (d_ws != nullptr && ws_size >= need) {
        unsigned short* wa = (unsigned short*)d_ws;
        unsigned short* wb = wa + (size_t)MDIM * KDIM;
        const int64_t nvec = ((int64_t)MDIM + NDIM) * KDIM / 8;  // 655,360
        cvt_kernel<<<(int)(nvec / 256), 256, 0, stream>>>(a, b, wa, wb);  // 2560 blocks
        gemm_bt<<<(MDIM / BM) * (NDIM / BN), 256, 0, stream>>>(wa, wb, out); // 4096 blocks
    } else {
        naive_f32<<<(int64_t)MDIM * NDIM / 256, 256, 0, stream>>>(a, b, out);
    }
}

// Round 2
// 295.546 us; speedup vs baseline: 1.0108x; 1.0108x over previous
//
#include <hip/hip_runtime.h>
#include <hip/hip_bf16.h>
#include <stdint.h>

// out[b,c] = sum_{k<256} batchs[b,k] * label2embed[c,k]
// A = batchs [16384, 256] fp32 row-major, Bm = label2embed [4096, 256] fp32 row-major
// out [16384, 4096] fp32. GEMM-BT, K=256. Output-write-bound: floor ~46 us (268 MB @ 5.8 TB/s).
#define MDIM 16384
#define NDIM 4096
#define KDIM 256

#define BM 128
#define BN 128
#define BK 32
#define KSTEPS (KDIM / BK)   // 8

typedef __attribute__((ext_vector_type(8))) short bf16x8;
typedef __attribute__((ext_vector_type(4))) float f32x4;

__device__ __forceinline__ unsigned short f2bf_rne(float f) {
    union { float f; uint32_t u; } v; v.f = f;
    uint32_t u = v.u;
    u += 0x7fffu + ((u >> 16) & 1u);   // round-to-nearest-even (finite inputs)
    return (unsigned short)(u >> 16);
}

// Pass 1: fp32 -> bf16 for both inputs, into workspace. 8 elems/thread, 16B stores.
// Total traffic: 21 MB read + 10.5 MB write -> ~6 us.
__global__ __launch_bounds__(256) void cvt_kernel(const float* __restrict__ a,
                                                  const float* __restrict__ b,
                                                  unsigned short* __restrict__ wa,
                                                  unsigned short* __restrict__ wb) {
    const int64_t nA = (int64_t)MDIM * KDIM;
    int64_t i = ((int64_t)blockIdx.x * 256 + threadIdx.x) * 8;
    const float* src; unsigned short* dst; int64_t off;
    if (i < nA) { src = a; dst = wa; off = i; }
    else        { src = b; dst = wb; off = i - nA; }
    float4 f0 = *(const float4*)(src + off);
    float4 f1 = *(const float4*)(src + off + 4);
    union { unsigned short h[8]; int4 v; } o;
    o.h[0] = f2bf_rne(f0.x); o.h[1] = f2bf_rne(f0.y);
    o.h[2] = f2bf_rne(f0.z); o.h[3] = f2bf_rne(f0.w);
    o.h[4] = f2bf_rne(f1.x); o.h[5] = f2bf_rne(f1.y);
    o.h[6] = f2bf_rne(f1.z); o.h[7] = f2bf_rne(f1.w);
    *(int4*)(dst + off) = o.v;
}

// Stage one 128x32 bf16 tile of A and B into LDS via width-16 global_load_lds.
// chunk ch in [0,512): row = ch>>2, col = (ch&3)*8; LDS byte off = ch*16
// -> per-wave uniform base + lane*16 (matches global_load_lds HW placement).
__device__ __forceinline__ void stage_tiles(const unsigned short* __restrict__ Ab,
                                            const unsigned short* __restrict__ Bb,
                                            unsigned short* sA, unsigned short* sB,
                                            int tid, int k0) {
#pragma unroll
    for (int c = 0; c < 2; ++c) {
        int ch  = tid + c * 256;
        int row = ch >> 2;
        int col = (ch & 3) << 3;
        __builtin_amdgcn_global_load_lds(
            (const __attribute__((address_space(1))) void*)(Ab + (size_t)row * KDIM + k0 + col),
            (__attribute__((address_space(3))) void*)(sA + ch * 8), 16, 0, 0);
        __builtin_amdgcn_global_load_lds(
            (const __attribute__((address_space(1))) void*)(Bb + (size_t)row * KDIM + k0 + col),
            (__attribute__((address_space(3))) void*)(sB + ch * 8), 16, 0, 0);
    }
}

// Pass 2: bf16 MFMA GEMM-BT. 128x128 tile/block, 256 thr = 4 waves, each wave a
// 64x64 quadrant = 4x4 MFMA 16x16 tiles. BK=32, 8 K-steps, DOUBLE-BUFFERED LDS:
// one barrier per step; loads for step k+1 issued right after the barrier so the
// next barrier's vmcnt(0) drain overlaps the whole compute phase of step k.
// __launch_bounds__(256,4): cap VGPR<=128 -> 16 waves/CU (4 blocks/CU).
__global__ __launch_bounds__(256, 4) void gemm_bt(const unsigned short* __restrict__ A,
                                                  const unsigned short* __restrict__ Bm,
                                                  float* __restrict__ out) {
    __shared__ __align__(16) unsigned short sA[2][BM * BK];  // 2 x 8 KiB
    __shared__ __align__(16) unsigned short sB[2][BN * BK];  // 2 x 8 KiB

    const int tid  = threadIdx.x;
    const int lane = tid & 63;
    const int wave = tid >> 6;
    const int wm   = wave >> 1;
    const int wn   = wave & 1;

    // XCD-aware swizzle: xcd = blockIdx % 8 (round-robin dispatch). Give each
    // XCD a private band of 16 bm's so every A-tile lands in exactly one L2.
    const int id  = blockIdx.x;
    const int xcd = id & 7;
    const int g   = id >> 3;            // 0..511
    const int bm  = (xcd << 4) | (g >> 5);  // 0..127
    const int bn  = g & 31;                 // 0..31

    const unsigned short* Ab = A  + (size_t)bm * BM * KDIM;
    const unsigned short* Bb = Bm + (size_t)bn * BN * KDIM;

    f32x4 acc[4][4] = {};

    const int quad = lane >> 4;
    const int r16  = lane & 15;

    stage_tiles(Ab, Bb, sA[0], sB[0], tid, 0);

#pragma unroll
    for (int step = 0; step < KSTEPS; ++step) {
        __syncthreads();  // drains vmcnt for buf[step&1]; WAR-protects buf[(step+1)&1]
        if (step + 1 < KSTEPS)
            stage_tiles(Ab, Bb, sA[(step + 1) & 1], sB[(step + 1) & 1], tid, (step + 1) * BK);

        const unsigned short* cA = sA[step & 1];
        const unsigned short* cB = sB[step & 1];

        // A-fragment layout: A[m = lane&15][k = quad*8 + j]  (one ds_read_b128 each)
        bf16x8 af[4], bf[4];
#pragma unroll
        for (int i = 0; i < 4; ++i)
            af[i] = *(const bf16x8*)(cA + ((wm * 64 + i * 16 + r16) * BK + quad * 8));
#pragma unroll
        for (int j = 0; j < 4; ++j)
            bf[j] = *(const bf16x8*)(cB + ((wn * 64 + j * 16 + r16) * BK + quad * 8));

#pragma unroll
        for (int i = 0; i < 4; ++i)
#pragma unroll
            for (int j = 0; j < 4; ++j)
                acc[i][j] = __builtin_amdgcn_mfma_f32_16x16x32_bf16(af[i], bf[j], acc[i][j], 0, 0, 0);
    }

    // Epilogue: C/D layout col = lane&15, row = quad*4 + reg  [m89/m91]
#pragma unroll
    for (int i = 0; i < 4; ++i) {
        int rowb = bm * BM + wm * 64 + i * 16 + quad * 4;
#pragma unroll
        for (int j = 0; j < 4; ++j) {
            int colb = bn * BN + wn * 64 + j * 16 + r16;
            float* p = out + (size_t)rowb * NDIM + colb;
#pragma unroll
            for (int rr = 0; rr < 4; ++rr)
                p[(size_t)rr * NDIM] = acc[i][j][rr];
        }
    }
}

// Fallback (only if ws too small): fp32 dot, one thread per output.
__global__ __launch_bounds__(256) void naive_f32(const float* __restrict__ a,
                                                 const float* __restrict__ b,
                                                 float* __restrict__ out) {
    int64_t idx = (int64_t)blockIdx.x * 256 + threadIdx.x;
    int c = (int)(idx & (NDIM - 1));
    int r = (int)(idx >> 12);
    const float4* ap = (const float4*)(a + (size_t)r * KDIM);
    const float4* bp = (const float4*)(b + (size_t)c * KDIM);
    float s = 0.f;
#pragma unroll 8
    for (int k = 0; k < KDIM / 4; ++k) {
        float4 x = ap[k], y = bp[k];
        s += x.x * y.x + x.y * y.y + x.z * y.z + x.w * y.w;
    }
    out[idx] = s;
}

extern "C" void kernel_launch(void* const* d_in, const int* in_sizes, int n_in,
                              void* d_out, int out_size, void* d_ws, size_t ws_size,
                              hipStream_t stream) {
    const float* a = (const float*)d_in[0];   // batchs  [16384, 2, 128]
    const float* b = (const float*)d_in[1];   // label2embed [4096, 2, 128]
    float* out = (float*)d_out;               // [16384, 4096]

    const size_t need = ((size_t)MDIM + NDIM) * KDIM * sizeof(unsigned short); // 10.5 MB
    if (d_ws != nullptr && ws_size >= need) {
        unsigned short* wa = (unsigned short*)d_ws;
        unsigned short* wb = wa + (size_t)MDIM * KDIM;
        const int64_t nvec = ((int64_t)MDIM + NDIM) * KDIM / 8;  // 655,360
        cvt_kernel<<<(int)(nvec / 256), 256, 0, stream>>>(a, b, wa, wb);       // 2560 blocks
        gemm_bt<<<(MDIM / BM) * (NDIM / BN), 256, 0, stream>>>(wa, wb, out);   // 4096 blocks
    } else {
        naive_f32<<<(int64_t)MDIM * NDIM / 256, 256, 0, stream>>>(a, b, out);
    }
}